// Round 8
// baseline (9043.480 us; speedup 1.0000x reference)
//
#include <hip/hip_runtime.h>
#include <math.h>

// Problem dims (fixed): N=64, T=512, D=512, H=512, 4H=2048 gate cols.
// Gate-col permutation: v = hd*4 + gate  (orig col o = gate*512 + hd)
//
// PANEL (fragment-major) layout for all MFMA operands, 16-row tiles, K=512:
//   flat(rt, kblk, lane, e) = (rt*16 + kblk)*512 + lane*8 + e
//   where rt = row>>4, kblk = k>>5, lane = ((k>>3)&3)*16 + (row&15), e = k&7.
// A fragment load for (rt, kblk) is then 64 lanes x 16B CONTIGUOUS (8 cache
// lines/instr instead of 64 — Round 6 was L1-transaction-bound).
constexpr int T_ = 512;
constexpr int H_ = 512;
constexpr int V_ = 2048;
constexpr int KW_ = 512;

using short8 = __attribute__((ext_vector_type(8))) short;     // 8 bf16 MFMA frag
using f32x4  = __attribute__((ext_vector_type(4))) float;     // MFMA acc / NT loads
using u16x8  = __attribute__((ext_vector_type(8))) unsigned short;

// ws layout (bytes):
//   [0, 4MB)        WxT panels bf16: hi then lo (each 1M shorts = 2MB)
//   [4MB, 8MB)      WhT panels bf16: hi then lo
//   [8MB, +256KB)   hstage: [2 parities][hi 32768 | lo 32768 shorts] panel layout
//   [+128KB)        cs: fp32 c[64][512]
//   [+16KB)         flags: int[4096] (64 WG flags, stride 32)
//   xs: panel bf16 x chunk: hi [CT*4 rt][16][512] then lo   (CT*128KB)
//   xw: fp32 [CT*64][2048]                                  (CT*512KB)
constexpr size_t OFF_WXT   = 0;
constexpr size_t OFF_WHT   = 4u * 1024 * 1024;
constexpr size_t OFF_HS    = 8u * 1024 * 1024;
constexpr size_t OFF_CS    = OFF_HS + 256u * 1024;
constexpr size_t OFF_FLAGS = OFF_CS + 128u * 1024;
constexpr size_t OFF_XS    = OFF_FLAGS + 16u * 1024;
constexpr int    NFLAGS    = 4096;

__device__ __forceinline__ void split_bf16(float x, unsigned short& hi, unsigned short& lo) {
    unsigned u  = __builtin_bit_cast(unsigned, x);
    unsigned rh = (u + 0x7fffu + ((u >> 16) & 1u)) >> 16;
    hi = (unsigned short)rh;
    float hf = __builtin_bit_cast(float, rh << 16);
    float l  = x - hf;                       // exact in fp32
    unsigned ul = __builtin_bit_cast(unsigned, l);
    unsigned rl = (ul + 0x7fffu + ((ul >> 16) & 1u)) >> 16;
    lo = (unsigned short)rl;
}

__device__ __forceinline__ float sigm(float x) { return 1.0f / (1.0f + __expf(-x)); }
__device__ __forceinline__ float tanh_fast(float x) {
    float xc = fminf(fmaxf(x, -15.0f), 15.0f);
    float e = __expf(-2.0f * xc);
    return (1.0f - e) / (1.0f + e);
}

// panel flat index (rows and k as described above)
__device__ __forceinline__ size_t pidx(int row, int k) {
    return (size_t)((row >> 4) * 16 + (k >> 5)) * 512 + (((k >> 3) & 3) * 16 + (row & 15)) * 8 + (k & 7);
}

// ---------------------------------------------------------------------------
// prep_wt: W (512 k x 2048 o fp32) -> panel bf16 hi/lo with v-permuted rows.
// ---------------------------------------------------------------------------
__global__ __launch_bounds__(256) void prep_wt(const float* __restrict__ W,
                                               unsigned short* __restrict__ WT_hi,
                                               unsigned short* __restrict__ WT_lo) {
    __shared__ float tile[32][33];
    const int ot = blockIdx.x;          // o-tile (64)
    const int kt = blockIdx.y;          // k-tile (16): kblk == kt
    const int lx = threadIdx.x;         // 0..31
    const int ly = threadIdx.y;         // 0..7
    #pragma unroll
    for (int i = 0; i < 4; ++i) {
        const int k = kt * 32 + ly + i * 8;
        const int o = ot * 32 + lx;
        tile[ly + i * 8][lx] = W[(size_t)k * V_ + o];
    }
    __syncthreads();
    #pragma unroll
    for (int i = 0; i < 4; ++i) {
        const int o = ot * 32 + ly + i * 8;
        const int v = ((o & 511) << 2) | (o >> 9);      // permuted row
        const int kk = kt * 32 + lx;
        unsigned short hi, lo;
        split_bf16(tile[lx][ly + i * 8], hi, lo);
        const size_t d = pidx(v, kk);
        WT_hi[d] = hi;
        WT_lo[d] = lo;
    }
}

// prep_h0: h0 (64x512 fp32) -> hstage parity-0 panels; zero cs + flags.
__global__ __launch_bounds__(256) void prep_h0(const float* __restrict__ h0,
                                               unsigned short* __restrict__ hs,
                                               float* __restrict__ cs,
                                               int* __restrict__ flags) {
    const int i = blockIdx.x * 256 + threadIdx.x;   // 0..32767
    const int n = i >> 9, hd = i & 511;
    unsigned short hi, lo;
    split_bf16(h0[i], hi, lo);
    const size_t d = pidx(n, hd);
    hs[d] = hi;
    hs[32768 + d] = lo;
    cs[i] = 0.0f;
    if (i < NFLAGS) flags[i] = 0;
}

// ---------------------------------------------------------------------------
// xsplit: x chunk [c0,c0+CT) -> panel bf16 hi/lo. Dest-linear (stores 16B
// contiguous per thread); source reads scatter 32B/lane (one pass, cheap).
// Panel rows r = tl*64 + n, rt = r>>4 in [0, CT*4).
// ---------------------------------------------------------------------------
__global__ __launch_bounds__(256) void xsplit(const float* __restrict__ x,
                                              unsigned short* __restrict__ xs,
                                              int c0, int CT) {
    const int gtid = blockIdx.x * 256 + threadIdx.x;
    const size_t xs_lo = (size_t)CT * 32768;
    const int tot = CT * 4096;                   // 8-elem groups
    for (int g = gtid; g < tot; g += 65536) {
        const int lane = g & 63;
        const int rtk  = g >> 6;
        const int kblk = rtk & 15;
        const int rt   = rtk >> 4;
        const int mc = lane & 15, kb = lane >> 4;
        const int r = rt * 16 + mc;              // tl*64 + n
        const int tl = r >> 6, n = r & 63;
        const int k0 = kblk * 32 + kb * 8;
        const float* xp = x + ((size_t)n * T_ + (c0 + tl)) * 512 + k0;
        const float4 va = *(const float4*)xp;
        const float4 vb = *(const float4*)(xp + 4);
        unsigned short hh[8], ll[8];
        split_bf16(va.x, hh[0], ll[0]); split_bf16(va.y, hh[1], ll[1]);
        split_bf16(va.z, hh[2], ll[2]); split_bf16(va.w, hh[3], ll[3]);
        split_bf16(vb.x, hh[4], ll[4]); split_bf16(vb.y, hh[5], ll[5]);
        split_bf16(vb.z, hh[6], ll[6]); split_bf16(vb.w, hh[7], ll[7]);
        u16x8 vh = {hh[0],hh[1],hh[2],hh[3],hh[4],hh[5],hh[6],hh[7]};
        u16x8 vl = {ll[0],ll[1],ll[2],ll[3],ll[4],ll[5],ll[6],ll[7]};
        *(u16x8*)(xs + (size_t)g * 8) = vh;
        *(u16x8*)(xs + xs_lo + (size_t)g * 8) = vl;
    }
}

// ---------------------------------------------------------------------------
// xw_gemm: xw[r][v] = xs[r][:] @ WxT[v][:] + b[v]   (split-bf16, 3-product)
// Panel A/B loads (contiguous 1KB/instr); C stored via per-wave LDS tile ->
// coalesced dwordx4 global stores.
// ---------------------------------------------------------------------------
__global__ __launch_bounds__(256, 1) void xw_gemm(const unsigned short* __restrict__ xs,
                                                  const unsigned short* __restrict__ wxt,
                                                  const float* __restrict__ bias,
                                                  float* __restrict__ xw, int CT) {
    const int tid = threadIdx.x;
    const int wid = tid >> 6, lane = tid & 63;
    const int mc = lane & 15, kb = lane >> 4;
    const int gwave = blockIdx.x * 4 + wid;
    const size_t xs_lo = (size_t)CT * 32768;

    __shared__ float ct[4][16][68];              // per-wave C tile

    const int tiles = CT * 128;                  // (CT*4 row-tiles) x 32 col64-groups
    for (int idx = gwave; idx < tiles; idx += 1024) {
        const int mtA = idx >> 5;
        const int ng  = idx & 31;
        const short* pa  = (const short*)xs + (size_t)mtA * 8192 + lane * 8;
        const short* pal = pa + xs_lo;
        const short* pb  = (const short*)wxt + (size_t)(ng * 4) * 8192 + lane * 8;
        f32x4 acc[4] = {};
        #pragma unroll
        for (int ks = 0; ks < 16; ++ks) {
            const short8 Ah = *(const short8*)(pa + ks * 512);
            const short8 Al = *(const short8*)(pal + ks * 512);
            #pragma unroll
            for (int n2 = 0; n2 < 4; ++n2) {
                const short8 bh = *(const short8*)(pb + (size_t)n2 * 8192 + ks * 512);
                const short8 bl = *(const short8*)(pb + 1048576 + (size_t)n2 * 8192 + ks * 512);
                acc[n2] = __builtin_amdgcn_mfma_f32_16x16x32_bf16(Ah, bh, acc[n2], 0, 0, 0);
                acc[n2] = __builtin_amdgcn_mfma_f32_16x16x32_bf16(Al, bh, acc[n2], 0, 0, 0);
                acc[n2] = __builtin_amdgcn_mfma_f32_16x16x32_bf16(Ah, bl, acc[n2], 0, 0, 0);
            }
        }
        // stage C tile (+bias) in per-wave LDS, then coalesced stores
        #pragma unroll
        for (int n2 = 0; n2 < 4; ++n2) {
            const int v = ng * 64 + n2 * 16 + mc;
            const float bv = bias[((v & 3) << 9) | (v >> 2)];
            #pragma unroll
            for (int j = 0; j < 4; ++j)
                ct[wid][kb * 4 + j][n2 * 16 + mc] = acc[n2][j] + bv;
        }
        #pragma unroll
        for (int s = 0; s < 4; ++s) {
            const int row16 = s * 4 + (lane >> 4);
            const int col4  = (lane & 15) * 4;
            const float4 cv = *(const float4*)&ct[wid][row16][col4];
            *(float4*)(xw + (size_t)(mtA * 16 + row16) * V_ + ng * 64 + col4) = cv;
        }
    }
}

// ---------------------------------------------------------------------------
// lstm_chunk: CT recurrent steps, ONE cooperative kernel. 64 WGs x 256 thr.
// WG wg owns v-cols [wg*32,+32) (hd [wg*8,+8)) x all 64 batch rows.
// K=512 split across 4 waves; Wh panels hoisted to registers (loop-invariant,
// launch_bounds(256,1) so the hoist sticks). hstage/xw/out accessed with
// NONTEMPORAL ops so the per-step release (wbl2) / acquire (inv) fences walk
// a nearly-clean L2. Barrier protocol identical to Round 6 (proven correct).
// ---------------------------------------------------------------------------
__global__ __launch_bounds__(256, 1) void lstm_chunk(const unsigned short* __restrict__ wht,
                                                     unsigned short* __restrict__ hs,
                                                     float* __restrict__ cs,
                                                     const float* __restrict__ xw,
                                                     float* __restrict__ out,
                                                     int* __restrict__ flags,
                                                     int c0, int CT) {
    const int tid = threadIdx.x;
    const int wid = tid >> 6, lane = tid & 63;
    const int wg = blockIdx.x;           // 0..63

    __shared__ float red[4][64][33];

    // ---- hoist Wh panel fragments into registers ----
    short8 Bh[4][2], Bl[4][2];           // [ks][nt]
    #pragma unroll
    for (int ks = 0; ks < 4; ++ks) {
        #pragma unroll
        for (int nt = 0; nt < 2; ++nt) {
            const size_t bo = (size_t)((wg * 2 + nt) * 16 + wid * 4 + ks) * 512 + lane * 8;
            Bh[ks][nt] = *(const short8*)((const short*)wht + bo);
            Bl[ks][nt] = *(const short8*)((const short*)wht + 1048576 + bo);
        }
    }

    // ---- gate-phase ownership: row r, hd quads qq & qq+4; c in registers ----
    const int r = tid >> 2, qq = tid & 3;
    float creg[2];
    creg[0] = cs[(size_t)r * 512 + wg * 8 + qq];
    creg[1] = cs[(size_t)r * 512 + wg * 8 + qq + 4];
    // h panel write base for (n=r, hd = wg*8 + {qq, qq+4})
    const size_t hwb = (size_t)((r >> 4) * 16 + (wg >> 2)) * 512 + ((wg & 3) * 16 + (r & 15)) * 8;

    for (int tl = 0; tl < CT; ++tl) {
        const int t = c0 + tl;
        const short* hbase = (const short*)(hs + (size_t)(t & 1) * 65536);

        // prefetch xw (independent of h) — ext-vector ptr for nontemporal builtin
        const float* xwr = xw + ((size_t)tl * 64 + r) * V_ + wg * 32;
        const f32x4 xv0 = __builtin_nontemporal_load((const f32x4*)(xwr + qq * 4));
        const f32x4 xv1 = __builtin_nontemporal_load((const f32x4*)(xwr + (qq + 4) * 4));

        f32x4 acc[4][2] = {};
        #pragma unroll
        for (int ks = 0; ks < 4; ++ks) {
            #pragma unroll
            for (int rt = 0; rt < 4; ++rt) {
                const size_t ao = (size_t)(rt * 16 + wid * 4 + ks) * 512 + lane * 8;
                const short8 Ah = __builtin_nontemporal_load((const short8*)(hbase + ao));
                const short8 Al = __builtin_nontemporal_load((const short8*)(hbase + 32768 + ao));
                #pragma unroll
                for (int nt = 0; nt < 2; ++nt) {
                    acc[rt][nt] = __builtin_amdgcn_mfma_f32_16x16x32_bf16(Ah, Bh[ks][nt], acc[rt][nt], 0, 0, 0);
                    acc[rt][nt] = __builtin_amdgcn_mfma_f32_16x16x32_bf16(Al, Bh[ks][nt], acc[rt][nt], 0, 0, 0);
                    acc[rt][nt] = __builtin_amdgcn_mfma_f32_16x16x32_bf16(Ah, Bl[ks][nt], acc[rt][nt], 0, 0, 0);
                }
            }
        }
        // K-quarter partials -> LDS (C layout: row = kb*4+j, col = mc)
        {
            const int mc = lane & 15, kb = lane >> 4;
            #pragma unroll
            for (int rt = 0; rt < 4; ++rt)
                #pragma unroll
                for (int nt = 0; nt < 2; ++nt)
                    #pragma unroll
                    for (int j = 0; j < 4; ++j)
                        red[wid][rt * 16 + kb * 4 + j][nt * 16 + mc] = acc[rt][nt][j];
        }
        __syncthreads();

        // gates
        {
            float* op = out + ((size_t)r * T_ + t) * H_ + wg * 8;
            unsigned short* hdst = hs + (size_t)((t + 1) & 1) * 65536 + hwb;
            #pragma unroll
            for (int half = 0; half < 2; ++half) {
                const int q = qq + half * 4;
                float a[4];
                #pragma unroll
                for (int c2 = 0; c2 < 4; ++c2)
                    a[c2] = red[0][r][q * 4 + c2] + red[1][r][q * 4 + c2]
                          + red[2][r][q * 4 + c2] + red[3][r][q * 4 + c2];
                const f32x4 xv = half ? xv1 : xv0;
                const float iv = sigm(a[0] + xv[0]);
                const float fv = sigm(a[1] + xv[1]);
                const float ov = sigm(a[2] + xv[2]);
                const float gv = tanh_fast(a[3] + xv[3]);
                const float cc = fv * creg[half] + iv * gv;
                creg[half] = cc;
                const float hv = ov * tanh_fast(cc);
                __builtin_nontemporal_store(hv, op + q);
                unsigned short hh, hl;
                split_bf16(hv, hh, hl);
                __builtin_nontemporal_store(hh, hdst + q);
                __builtin_nontemporal_store(hl, hdst + 32768 + q);
            }
        }
        __syncthreads();   // red[] reuse safety for next step

        // ---- step barrier (identical to Round 6) ----
        __threadfence();                       // release: waitcnt + L2 writeback
        __syncthreads();
        if (tid == 0)
            __hip_atomic_store(&flags[wg * 32], t + 1,
                               __ATOMIC_RELAXED, __HIP_MEMORY_SCOPE_AGENT);
        bool mine = true;
        do {
            if (tid < 64) {
                int v = __hip_atomic_load(&flags[tid * 32],
                                          __ATOMIC_ACQUIRE, __HIP_MEMORY_SCOPE_AGENT);
                mine = (v >= t + 1);
                if (!mine) __builtin_amdgcn_s_sleep(2);
            }
        } while (!__syncthreads_and(mine));
        __builtin_amdgcn_fence(__ATOMIC_ACQUIRE, "agent");   // invalidate stale L1/L2
        __syncthreads();
    }

    cs[(size_t)r * 512 + wg * 8 + qq]     = creg[0];
    cs[(size_t)r * 512 + wg * 8 + qq + 4] = creg[1];
}

extern "C" void kernel_launch(void* const* d_in, const int* in_sizes, int n_in,
                              void* d_out, int out_size, void* d_ws, size_t ws_size,
                              hipStream_t stream) {
    const float* x  = (const float*)d_in[0];   // (N,T,D)
    const float* h0 = (const float*)d_in[1];   // (N,H)
    const float* Wx = (const float*)d_in[2];   // (D,4H)
    const float* Wh = (const float*)d_in[3];   // (H,4H)
    const float* b  = (const float*)d_in[4];   // (4H,)
    float* out = (float*)d_out;                // (N,T,H)

    char* ws = (char*)d_ws;
    unsigned short* wxt = (unsigned short*)(ws + OFF_WXT);   // hi; lo at +1048576 elems
    unsigned short* wht = (unsigned short*)(ws + OFF_WHT);
    unsigned short* hs  = (unsigned short*)(ws + OFF_HS);
    float* cs           = (float*)(ws + OFF_CS);
    int* flags          = (int*)(ws + OFF_FLAGS);
    unsigned short* xs  = (unsigned short*)(ws + OFF_XS);

    // chunk size: cap at 128 so xw (CT*512KB) stays MALL-resident
    int CT = 8;
    const int cands[5] = {128, 64, 32, 16, 8};
    for (int i = 0; i < 5; ++i) {
        size_t need = OFF_XS + (size_t)cands[i] * (131072 + 524288);
        if (need <= ws_size) { CT = cands[i]; break; }
    }
    float* xw = (float*)(ws + OFF_XS + (size_t)CT * 131072);

    prep_wt<<<dim3(64, 16), dim3(32, 8), 0, stream>>>(Wx, wxt, wxt + (size_t)V_ * KW_);
    prep_wt<<<dim3(64, 16), dim3(32, 8), 0, stream>>>(Wh, wht, wht + (size_t)V_ * KW_);
    prep_h0<<<128, 256, 0, stream>>>(h0, hs, cs, flags);

    for (int c0 = 0; c0 < T_; c0 += CT) {
        xsplit<<<256, 256, 0, stream>>>(x, xs, c0, CT);
        xw_gemm<<<256, 256, 0, stream>>>(xs, wxt, b, xw, CT);
        int cc0 = c0, cct = CT;
        void* kwh = (void*)wht; void* khs = (void*)hs; void* kcs = (void*)cs;
        void* kxw = (void*)xw; void* ko = (void*)out; void* kfl = (void*)flags;
        void* args[] = { &kwh, &khs, &kcs, &kxw, &ko, &kfl, &cc0, &cct };
        (void)hipLaunchCooperativeKernel((void*)lstm_chunk, dim3(64), dim3(256), args, 0, stream);
    }
}

// Round 9
// 7247.511 us; speedup vs baseline: 1.2478x; 1.2478x over previous
//
#include <hip/hip_runtime.h>
#include <math.h>

// Problem dims (fixed): N=64, T=512, D=512, H=512, 4H=2048 gate cols.
// Gate-col permutation: v = hd*4 + gate  (orig col o = gate*512 + hd)
//
// PANEL (fragment-major) layout for all MFMA operands, 16-row tiles, K=512:
//   flat(rt, kblk, lane, e) = (rt*16 + kblk)*512 + lane*8 + e
//   where rt = row>>4, kblk = k>>5, lane = ((k>>3)&3)*16 + (row&15), e = k&7.
// A fragment load is 64 lanes x 16B CONTIGUOUS (8 cache lines/instr).
constexpr int T_ = 512;
constexpr int H_ = 512;
constexpr int V_ = 2048;
constexpr int KW_ = 512;

using short8 = __attribute__((ext_vector_type(8))) short;     // 8 bf16 MFMA frag
using f32x4  = __attribute__((ext_vector_type(4))) float;     // MFMA acc
using u16x8  = __attribute__((ext_vector_type(8))) unsigned short;

// ws layout (bytes):
//   [0, 4MB)        WxT panels bf16: hi then lo (each 1M shorts = 2MB)
//   [4MB, 8MB)      WhT panels bf16: hi then lo
//   [8MB, +256KB)   hstage: [2 parities][hi 32768 | lo 32768 shorts] panel layout
//   [+128KB)        cs: fp32 c[64][512]
//   [+16KB)         flags: int[4096] (64 WG flags, stride 32)
//   xs: panel bf16 x chunk: hi [CT*4 rt][16][512] then lo   (CT*128KB)
//   xw: fp32 [CT*64][2048]                                  (CT*512KB)
constexpr size_t OFF_WXT   = 0;
constexpr size_t OFF_WHT   = 4u * 1024 * 1024;
constexpr size_t OFF_HS    = 8u * 1024 * 1024;
constexpr size_t OFF_CS    = OFF_HS + 256u * 1024;
constexpr size_t OFF_FLAGS = OFF_CS + 128u * 1024;
constexpr size_t OFF_XS    = OFF_FLAGS + 16u * 1024;
constexpr int    NFLAGS    = 4096;

__device__ __forceinline__ void split_bf16(float x, unsigned short& hi, unsigned short& lo) {
    unsigned u  = __builtin_bit_cast(unsigned, x);
    unsigned rh = (u + 0x7fffu + ((u >> 16) & 1u)) >> 16;
    hi = (unsigned short)rh;
    float hf = __builtin_bit_cast(float, rh << 16);
    float l  = x - hf;                       // exact in fp32
    unsigned ul = __builtin_bit_cast(unsigned, l);
    unsigned rl = (ul + 0x7fffu + ((ul >> 16) & 1u)) >> 16;
    lo = (unsigned short)rl;
}

__device__ __forceinline__ float sigm(float x) { return 1.0f / (1.0f + __expf(-x)); }
__device__ __forceinline__ float tanh_fast(float x) {
    float xc = fminf(fmaxf(x, -15.0f), 15.0f);
    float e = __expf(-2.0f * xc);
    return (1.0f - e) / (1.0f + e);
}

// panel flat index
__device__ __forceinline__ size_t pidx(int row, int k) {
    return (size_t)((row >> 4) * 16 + (k >> 5)) * 512 + (((k >> 3) & 3) * 16 + (row & 15)) * 8 + (k & 7);
}

// ---------------------------------------------------------------------------
// prep_wt: W (512 k x 2048 o fp32) -> panel bf16 hi/lo with v-permuted rows.
// ---------------------------------------------------------------------------
__global__ __launch_bounds__(256) void prep_wt(const float* __restrict__ W,
                                               unsigned short* __restrict__ WT_hi,
                                               unsigned short* __restrict__ WT_lo) {
    __shared__ float tile[32][33];
    const int ot = blockIdx.x;          // o-tile (64)
    const int kt = blockIdx.y;          // k-tile (16)
    const int lx = threadIdx.x;         // 0..31
    const int ly = threadIdx.y;         // 0..7
    #pragma unroll
    for (int i = 0; i < 4; ++i) {
        const int k = kt * 32 + ly + i * 8;
        const int o = ot * 32 + lx;
        tile[ly + i * 8][lx] = W[(size_t)k * V_ + o];
    }
    __syncthreads();
    #pragma unroll
    for (int i = 0; i < 4; ++i) {
        const int o = ot * 32 + ly + i * 8;
        const int v = ((o & 511) << 2) | (o >> 9);      // permuted row
        const int kk = kt * 32 + lx;
        unsigned short hi, lo;
        split_bf16(tile[lx][ly + i * 8], hi, lo);
        const size_t d = pidx(v, kk);
        WT_hi[d] = hi;
        WT_lo[d] = lo;
    }
}

// prep_h0: h0 (64x512 fp32) -> hstage parity-0 panels; zero cs + flags.
__global__ __launch_bounds__(256) void prep_h0(const float* __restrict__ h0,
                                               unsigned short* __restrict__ hs,
                                               float* __restrict__ cs,
                                               int* __restrict__ flags) {
    const int i = blockIdx.x * 256 + threadIdx.x;   // 0..32767
    const int n = i >> 9, hd = i & 511;
    unsigned short hi, lo;
    split_bf16(h0[i], hi, lo);
    const size_t d = pidx(n, hd);
    hs[d] = hi;
    hs[32768 + d] = lo;
    cs[i] = 0.0f;
    if (i < NFLAGS) flags[i] = 0;
}

// ---------------------------------------------------------------------------
// xsplit: x chunk [c0,c0+CT) -> panel bf16 hi/lo (dest-linear stores).
// ---------------------------------------------------------------------------
__global__ __launch_bounds__(256) void xsplit(const float* __restrict__ x,
                                              unsigned short* __restrict__ xs,
                                              int c0, int CT) {
    const int gtid = blockIdx.x * 256 + threadIdx.x;
    const size_t xs_lo = (size_t)CT * 32768;
    const int tot = CT * 4096;                   // 8-elem groups
    for (int g = gtid; g < tot; g += 65536) {
        const int lane = g & 63;
        const int rtk  = g >> 6;
        const int kblk = rtk & 15;
        const int rt   = rtk >> 4;
        const int mc = lane & 15, kb = lane >> 4;
        const int r = rt * 16 + mc;              // tl*64 + n
        const int tl = r >> 6, n = r & 63;
        const int k0 = kblk * 32 + kb * 8;
        const float* xp = x + ((size_t)n * T_ + (c0 + tl)) * 512 + k0;
        const float4 va = *(const float4*)xp;
        const float4 vb = *(const float4*)(xp + 4);
        unsigned short hh[8], ll[8];
        split_bf16(va.x, hh[0], ll[0]); split_bf16(va.y, hh[1], ll[1]);
        split_bf16(va.z, hh[2], ll[2]); split_bf16(va.w, hh[3], ll[3]);
        split_bf16(vb.x, hh[4], ll[4]); split_bf16(vb.y, hh[5], ll[5]);
        split_bf16(vb.z, hh[6], ll[6]); split_bf16(vb.w, hh[7], ll[7]);
        u16x8 vh = {hh[0],hh[1],hh[2],hh[3],hh[4],hh[5],hh[6],hh[7]};
        u16x8 vl = {ll[0],ll[1],ll[2],ll[3],ll[4],ll[5],ll[6],ll[7]};
        *(u16x8*)(xs + (size_t)g * 8) = vh;
        *(u16x8*)(xs + xs_lo + (size_t)g * 8) = vl;
    }
}

// ---------------------------------------------------------------------------
// xw_gemm: xw[r][v] = xs[r][:] @ WxT[v][:] + b[v]   (split-bf16, 3-product)
// Panel A/B loads; C stored via per-wave LDS tile -> coalesced dwordx4.
// ---------------------------------------------------------------------------
__global__ __launch_bounds__(256, 1) void xw_gemm(const unsigned short* __restrict__ xs,
                                                  const unsigned short* __restrict__ wxt,
                                                  const float* __restrict__ bias,
                                                  float* __restrict__ xw, int CT) {
    const int tid = threadIdx.x;
    const int wid = tid >> 6, lane = tid & 63;
    const int mc = lane & 15, kb = lane >> 4;
    const int gwave = blockIdx.x * 4 + wid;
    const size_t xs_lo = (size_t)CT * 32768;

    __shared__ float ct[4][16][68];              // per-wave C tile

    const int tiles = CT * 128;                  // (CT*4 row-tiles) x 32 col64-groups
    for (int idx = gwave; idx < tiles; idx += 1024) {
        const int mtA = idx >> 5;
        const int ng  = idx & 31;
        const short* pa  = (const short*)xs + (size_t)mtA * 8192 + lane * 8;
        const short* pal = pa + xs_lo;
        const short* pb  = (const short*)wxt + (size_t)(ng * 4) * 8192 + lane * 8;
        f32x4 acc[4] = {};
        #pragma unroll
        for (int ks = 0; ks < 16; ++ks) {
            const short8 Ah = *(const short8*)(pa + ks * 512);
            const short8 Al = *(const short8*)(pal + ks * 512);
            #pragma unroll
            for (int n2 = 0; n2 < 4; ++n2) {
                const short8 bh = *(const short8*)(pb + (size_t)n2 * 8192 + ks * 512);
                const short8 bl = *(const short8*)(pb + 1048576 + (size_t)n2 * 8192 + ks * 512);
                acc[n2] = __builtin_amdgcn_mfma_f32_16x16x32_bf16(Ah, bh, acc[n2], 0, 0, 0);
                acc[n2] = __builtin_amdgcn_mfma_f32_16x16x32_bf16(Al, bh, acc[n2], 0, 0, 0);
                acc[n2] = __builtin_amdgcn_mfma_f32_16x16x32_bf16(Ah, bl, acc[n2], 0, 0, 0);
            }
        }
        #pragma unroll
        for (int n2 = 0; n2 < 4; ++n2) {
            const int v = ng * 64 + n2 * 16 + mc;
            const float bv = bias[((v & 3) << 9) | (v >> 2)];
            #pragma unroll
            for (int j = 0; j < 4; ++j)
                ct[wid][kb * 4 + j][n2 * 16 + mc] = acc[n2][j] + bv;
        }
        #pragma unroll
        for (int s = 0; s < 4; ++s) {
            const int row16 = s * 4 + (lane >> 4);
            const int col4  = (lane & 15) * 4;
            const float4 cv = *(const float4*)&ct[wid][row16][col4];
            *(float4*)(xw + (size_t)(mtA * 16 + row16) * V_ + ng * 64 + col4) = cv;
        }
    }
}

// ---------------------------------------------------------------------------
// lstm_chunk: CT recurrent steps, ONE cooperative kernel. 64 WGs x 256 thr.
// Changes vs R8: (1) B fragments PINNED in VGPRs via asm "+v" (remat illegal),
// (2) no nontemporal ops (h/xw stay cache-hot), (3) flag poll RELAXED with the
// single trailing acquire fence doing the ordering (R6-proven position),
// (4) red[] padded to 36 (2-way max bank aliasing).
// ---------------------------------------------------------------------------
__global__ __launch_bounds__(256, 1) void lstm_chunk(const unsigned short* __restrict__ wht,
                                                     unsigned short* __restrict__ hs,
                                                     float* __restrict__ cs,
                                                     const float* __restrict__ xw,
                                                     float* __restrict__ out,
                                                     int* __restrict__ flags,
                                                     int c0, int CT) {
    const int tid = threadIdx.x;
    const int wid = tid >> 6, lane = tid & 63;
    const int wg = blockIdx.x;           // 0..63

    __shared__ float red[4][64][36];

    // ---- load Wh panel fragments and PIN them in registers ----
    short8 Bh[4][2], Bl[4][2];           // [ks][nt] = 16 frags = 64 VGPRs
    #pragma unroll
    for (int ks = 0; ks < 4; ++ks) {
        #pragma unroll
        for (int nt = 0; nt < 2; ++nt) {
            const size_t bo = (size_t)((wg * 2 + nt) * 16 + wid * 4 + ks) * 512 + lane * 8;
            Bh[ks][nt] = *(const short8*)((const short*)wht + bo);
            Bl[ks][nt] = *(const short8*)((const short*)wht + 1048576 + bo);
            asm volatile("" : "+v"(Bh[ks][nt]));   // opaque: remat of the load is now illegal
            asm volatile("" : "+v"(Bl[ks][nt]));
        }
    }

    // ---- gate-phase ownership: row r, hd quads qq & qq+4; c in registers ----
    const int r = tid >> 2, qq = tid & 3;
    float creg[2];
    creg[0] = cs[(size_t)r * 512 + wg * 8 + qq];
    creg[1] = cs[(size_t)r * 512 + wg * 8 + qq + 4];
    // h panel write base for (n=r, hd = wg*8 + {qq, qq+4})
    const size_t hwb = (size_t)((r >> 4) * 16 + (wg >> 2)) * 512 + ((wg & 3) * 16 + (r & 15)) * 8;

    for (int tl = 0; tl < CT; ++tl) {
        const int t = c0 + tl;
        const short* hbase = (const short*)(hs + (size_t)(t & 1) * 65536);

        // prefetch xw (independent of h)
        const float* xwr = xw + ((size_t)tl * 64 + r) * V_ + wg * 32;
        const f32x4 xv0 = *(const f32x4*)(xwr + qq * 4);
        const f32x4 xv1 = *(const f32x4*)(xwr + (qq + 4) * 4);

        f32x4 acc[4][2] = {};
        #pragma unroll
        for (int ks = 0; ks < 4; ++ks) {
            #pragma unroll
            for (int rt = 0; rt < 4; ++rt) {
                const size_t ao = (size_t)(rt * 16 + wid * 4 + ks) * 512 + lane * 8;
                const short8 Ah = *(const short8*)(hbase + ao);
                const short8 Al = *(const short8*)(hbase + 32768 + ao);
                #pragma unroll
                for (int nt = 0; nt < 2; ++nt) {
                    acc[rt][nt] = __builtin_amdgcn_mfma_f32_16x16x32_bf16(Ah, Bh[ks][nt], acc[rt][nt], 0, 0, 0);
                    acc[rt][nt] = __builtin_amdgcn_mfma_f32_16x16x32_bf16(Al, Bh[ks][nt], acc[rt][nt], 0, 0, 0);
                    acc[rt][nt] = __builtin_amdgcn_mfma_f32_16x16x32_bf16(Ah, Bl[ks][nt], acc[rt][nt], 0, 0, 0);
                }
            }
        }
        // K-quarter partials -> LDS (C layout: row = kb*4+j, col = mc)
        {
            const int mc = lane & 15, kb = lane >> 4;
            #pragma unroll
            for (int rt = 0; rt < 4; ++rt)
                #pragma unroll
                for (int nt = 0; nt < 2; ++nt)
                    #pragma unroll
                    for (int j = 0; j < 4; ++j)
                        red[wid][rt * 16 + kb * 4 + j][nt * 16 + mc] = acc[rt][nt][j];
        }
        __syncthreads();

        // gates
        {
            float* op = out + ((size_t)r * T_ + t) * H_ + wg * 8;
            unsigned short* hdst = hs + (size_t)((t + 1) & 1) * 65536 + hwb;
            #pragma unroll
            for (int half = 0; half < 2; ++half) {
                const int q = qq + half * 4;
                float a[4];
                #pragma unroll
                for (int c2 = 0; c2 < 4; ++c2)
                    a[c2] = red[0][r][q * 4 + c2] + red[1][r][q * 4 + c2]
                          + red[2][r][q * 4 + c2] + red[3][r][q * 4 + c2];
                const f32x4 xv = half ? xv1 : xv0;
                const float iv = sigm(a[0] + xv[0]);
                const float fv = sigm(a[1] + xv[1]);
                const float ov = sigm(a[2] + xv[2]);
                const float gv = tanh_fast(a[3] + xv[3]);
                const float cc = fv * creg[half] + iv * gv;
                creg[half] = cc;
                const float hv = ov * tanh_fast(cc);
                op[q] = hv;
                unsigned short hh, hl;
                split_bf16(hv, hh, hl);
                hdst[q] = hh;
                hdst[32768 + q] = hl;
            }
        }
        __syncthreads();   // red[] reuse safety for next step

        // ---- step barrier (R6 protocol; poll relaxed, single trailing acquire) ----
        __threadfence();                       // release: waitcnt + L2 writeback
        __syncthreads();
        if (tid == 0)
            __hip_atomic_store(&flags[wg * 32], t + 1,
                               __ATOMIC_RELAXED, __HIP_MEMORY_SCOPE_AGENT);
        bool mine = true;
        do {
            if (tid < 64) {
                int v = __hip_atomic_load(&flags[tid * 32],
                                          __ATOMIC_RELAXED, __HIP_MEMORY_SCOPE_AGENT);
                mine = (v >= t + 1);
                if (!mine) __builtin_amdgcn_s_sleep(2);
            }
        } while (!__syncthreads_and(mine));
        __builtin_amdgcn_fence(__ATOMIC_ACQUIRE, "agent");   // invalidate stale L1/L2
        __syncthreads();
    }

    cs[(size_t)r * 512 + wg * 8 + qq]     = creg[0];
    cs[(size_t)r * 512 + wg * 8 + qq + 4] = creg[1];
}

extern "C" void kernel_launch(void* const* d_in, const int* in_sizes, int n_in,
                              void* d_out, int out_size, void* d_ws, size_t ws_size,
                              hipStream_t stream) {
    const float* x  = (const float*)d_in[0];   // (N,T,D)
    const float* h0 = (const float*)d_in[1];   // (N,H)
    const float* Wx = (const float*)d_in[2];   // (D,4H)
    const float* Wh = (const float*)d_in[3];   // (H,4H)
    const float* b  = (const float*)d_in[4];   // (4H,)
    float* out = (float*)d_out;                // (N,T,H)

    char* ws = (char*)d_ws;
    unsigned short* wxt = (unsigned short*)(ws + OFF_WXT);   // hi; lo at +1048576 elems
    unsigned short* wht = (unsigned short*)(ws + OFF_WHT);
    unsigned short* hs  = (unsigned short*)(ws + OFF_HS);
    float* cs           = (float*)(ws + OFF_CS);
    int* flags          = (int*)(ws + OFF_FLAGS);
    unsigned short* xs  = (unsigned short*)(ws + OFF_XS);

    // largest chunk that fits (CT=512 -> single cooperative launch)
    int CT = 8;
    const int cands[7] = {512, 256, 128, 64, 32, 16, 8};
    for (int i = 0; i < 7; ++i) {
        size_t need = OFF_XS + (size_t)cands[i] * (131072 + 524288);
        if (need <= ws_size) { CT = cands[i]; break; }
    }
    float* xw = (float*)(ws + OFF_XS + (size_t)CT * 131072);

    prep_wt<<<dim3(64, 16), dim3(32, 8), 0, stream>>>(Wx, wxt, wxt + (size_t)V_ * KW_);
    prep_wt<<<dim3(64, 16), dim3(32, 8), 0, stream>>>(Wh, wht, wht + (size_t)V_ * KW_);
    prep_h0<<<128, 256, 0, stream>>>(h0, hs, cs, flags);

    for (int c0 = 0; c0 < T_; c0 += CT) {
        xsplit<<<256, 256, 0, stream>>>(x, xs, c0, CT);
        xw_gemm<<<256, 256, 0, stream>>>(xs, wxt, b, xw, CT);
        int cc0 = c0, cct = CT;
        void* kwh = (void*)wht; void* khs = (void*)hs; void* kcs = (void*)cs;
        void* kxw = (void*)xw; void* ko = (void*)out; void* kfl = (void*)flags;
        void* args[] = { &kwh, &khs, &kcs, &kxw, &ko, &kfl, &cc0, &cct };
        (void)hipLaunchCooperativeKernel((void*)lstm_chunk, dim3(64), dim3(256), args, 0, stream);
    }
}